// Round 25
// baseline (358.767 us; speedup 1.0000x reference)
//
#include <hip/hip_runtime.h>
#include <math.h>

#define NTOK   262144
#define DIM    64
#define NCODE  1024
#define LOSSOFF (NTOK*DIM)          // 16777216
#define IDXOFF  (NTOK*DIM + 1)

// Pure-bf16 scan margin: ref fp32 reorder (2*ulp(D<128) = 3.05e-5) +
// bf16 quantization pair-diff (sigma ~2.4e-5: x*(c-ch) + ch*(x-xh)).
// 3e-4 = 11-sigma headroom. Flag ~13% (R6 calib 8e-5 -> 3.4%, linear);
// refine is exact + parallel so flags are cheap.
#define MARGIN 3e-4f
#define RCAP   65536

// ws float-offsets
#define OFF_BC     0               // 1024 f
#define OFF_CBHI   1024            // ushort[65536] = 32768 f (plain rows)
#define OFF_CBMID  33792           // (unused in bf16-scan variant)
#define OFF_RCNT   66560           // 1 int
#define OFF_CORR   66561           // 1 float
#define OFF_RLIST  66562           // 65536 int
#define OFF_BLK    132098          // 2048 f
#define WS_FLOATS  134146

typedef __attribute__((ext_vector_type(8))) short short8;
typedef __attribute__((ext_vector_type(4))) float f32x4;

__device__ __forceinline__ ushort bf16rn(float f) {
    unsigned u = __float_as_uint(f);
    return (ushort)((u + 0x7fffu + ((u >> 16) & 1u)) >> 16);
}
__device__ __forceinline__ float bf16tof(ushort h) {
    return __uint_as_float(((unsigned)h) << 16);
}

// prep: bf16 hi plane of codebook (plain row-major) + exact R2 Bc chain.
__global__ __launch_bounds__(256) void vq_prep_cb(const float* __restrict__ cb,
                                                  float* __restrict__ ws) {
    int c = blockIdx.x * 256 + threadIdx.x;
    if (c == 0) { ((int*)ws)[OFF_RCNT] = 0; ws[OFF_CORR] = 0.f; }
    if (c >= NCODE) return;
    ushort* cbh = (ushort*)(ws + OFF_CBHI);
    const float4* p = (const float4*)(cb + (size_t)c * DIM);
    float a0 = 0.f, a1 = 0.f, a2 = 0.f, a3 = 0.f;
#pragma unroll
    for (int i = 0; i < 16; i++) {
        float4 v = p[i];
        a0 = fmaf(v.x, v.x, a0); a1 = fmaf(v.y, v.y, a1);
        a2 = fmaf(v.z, v.z, a2); a3 = fmaf(v.w, v.w, a3);
        ushort4 h;
        h.x = bf16rn(v.x); h.y = bf16rn(v.y);
        h.z = bf16rn(v.z); h.w = bf16rn(v.w);
        ((ushort4*)(cbh + (size_t)c * 64))[i] = h;
    }
    ws[OFF_BC + c] = (a0 + a1) + (a2 + a3);   // exact R2 prep chain
}

// Pure-bf16 MFMA scan (R18 champion structure, 1/3 the MFMAs, 1/2 the LDS):
// 2 MFMAs + 2 ds_read_b128 per 16x32-token sub-tile; single-barrier
// ping-pong, prefetch 2 rounds ahead; margin widened so the exact refine
// pass absorbs all bf16-quantization ambiguity.
__global__ __launch_bounds__(256)
__attribute__((amdgpu_waves_per_eu(4)))
void vq_mfma(const float* __restrict__ x,
             const float* __restrict__ cbf,
             float* __restrict__ out,
             float* __restrict__ ws) {
    __shared__ uint4 smem[8][128];   // 16KB: two 4-tile sets, 2KB/tile (hi only)
    __shared__ int idxs[128];
    __shared__ float red[4];
    const float* Bc = ws + OFF_BC;
    const ushort* cbh = (const ushort*)(ws + OFF_CBHI);

    int tid = threadIdx.x, lane = tid & 63, wv = tid >> 6;
    int col = lane & 15, q = lane >> 4, q4 = q * 4;
    int tokb = blockIdx.x * 128 + wv * 32;

    // X fragments: bf16 hi only
    short8 Xhi[2][2];
#pragma unroll
    for (int tt = 0; tt < 2; ++tt) {
        int token = tokb + tt * 16 + col;
        const float* xr = x + (size_t)token * 64;
#pragma unroll
        for (int s = 0; s < 2; ++s) {
            float4 v0 = *(const float4*)(xr + s * 32 + q * 8);
            float4 v1 = *(const float4*)(xr + s * 32 + q * 8 + 4);
            float vv[8] = {v0.x, v0.y, v0.z, v0.w, v1.x, v1.y, v1.z, v1.w};
            short8 hv;
#pragma unroll
            for (int j = 0; j < 8; ++j) hv[j] = (short)bf16rn(vv[j]);
            Xhi[tt][s] = hv;
        }
    }

    float best[2][4], sec[2][4];
    int bbase[2][4];
#pragma unroll
    for (int tt = 0; tt < 2; ++tt)
#pragma unroll
        for (int rr = 0; rr < 4; ++rr) {
            best[tt][rr] = 3.4e38f; sec[tt][rr] = 3.4e38f; bbase[tt][rr] = 0;
        }

    // staging: 512 granules/round (4 tiles x 16 codes x 8 slots), 2/thread
    int t0 = tid >> 7, e0 = tid & 127, sc = e0 >> 3, g = e0 & 7;
    int t1 = t0 + 2;
    const ushort* s0 = cbh + (size_t)(t0 * 16 + sc) * 64 + g * 8;
    const ushort* s1 = cbh + (size_t)(t1 * 16 + sc) * 64 + g * 8;
    int wi = sc * 8 + (g ^ (sc & 7));       // swizzled dest slot (R18 pattern)
    // ds_read offsets (proven zero-conflict layout)
    int ro_h0 = col * 8 + ((0 + q) ^ (col & 7));
    int ro_h1 = col * 8 + ((4 + q) ^ (col & 7));

    // prologue: round 0 -> set A; round-1 regs in flight
    uint4 r0 = *(const uint4*)(s0);
    uint4 r1 = *(const uint4*)(s1);
    smem[t0][wi] = r0; smem[t1][wi] = r1;
    r0 = *(const uint4*)(s0 + 4096);
    r1 = *(const uint4*)(s1 + 4096);
    __syncthreads();

    for (int rd = 0; rd < 16; ++rd) {
        int base = (rd & 1) << 2;    // set being read
        int nb = 4 - base;           // set being written (round rd+1 tiles)
        if (rd < 15) {
            smem[nb + t0][wi] = r0;
            smem[nb + t1][wi] = r1;
            if (rd < 14) {           // loads for round rd+2: 1 round of slack
                size_t off = (size_t)(rd + 2) * 4096;
                r0 = *(const uint4*)(s0 + off);
                r1 = *(const uint4*)(s1 + off);
            }
        }
#pragma unroll
        for (int sub = 0; sub < 4; ++sub) {
            int c0 = (rd * 4 + sub) * 16;
            float4 bq = *(const float4*)(Bc + c0 + q4);
            short8 Ah0 = *(const short8*)&smem[base + sub][ro_h0];
            short8 Ah1 = *(const short8*)&smem[base + sub][ro_h1];
            int bv = c0 + q4;
            float bqv[4] = {bq.x, bq.y, bq.z, bq.w};
#pragma unroll
            for (int tt = 0; tt < 2; ++tt) {
                f32x4 acc = {0.f, 0.f, 0.f, 0.f};
                acc = __builtin_amdgcn_mfma_f32_16x16x32_bf16(Ah0, Xhi[tt][0], acc, 0, 0, 0);
                acc = __builtin_amdgcn_mfma_f32_16x16x32_bf16(Ah1, Xhi[tt][1], acc, 0, 0, 0);
#pragma unroll
                for (int rr = 0; rr < 4; ++rr) {
                    float d = fmaf(-2.f, acc[rr], bqv[rr]);
                    bool lt = d < best[tt][rr];
                    sec[tt][rr] = __builtin_amdgcn_fmed3f(d, best[tt][rr], sec[tt][rr]);
                    best[tt][rr] = fminf(best[tt][rr], d);
                    bbase[tt][rr] = lt ? bv : bbase[tt][rr];
                }
            }
        }
        __syncthreads();   // single barrier per round
    }

#pragma unroll
    for (int tt = 0; tt < 2; ++tt) {
        float b = best[tt][0], s2 = sec[tt][0];
        int bi = bbase[tt][0];
#pragma unroll
        for (int rr = 1; rr < 4; ++rr) {
            float ob = best[tt][rr];
            int oi = bbase[tt][rr] + rr;
            s2 = fminf(fminf(s2, sec[tt][rr]), fmaxf(b, ob));
            bool lt2 = (ob < b) || (ob == b && oi < bi);
            b = lt2 ? ob : b; bi = lt2 ? oi : bi;
        }
#pragma unroll
        for (int off = 16; off <= 32; off <<= 1) {
            float ob = __shfl_xor(b, off, 64);
            float os = __shfl_xor(s2, off, 64);
            int   oi = __shfl_xor(bi, off, 64);
            s2 = fminf(fminf(s2, os), fmaxf(b, ob));
            bool lt = (ob < b) || (ob == b && oi < bi);
            b = lt ? ob : b; bi = lt ? oi : bi;
        }
        if (lane < 16) {
            int token = tokb + tt * 16 + lane;
            out[IDXOFF + token] = (float)bi;
            idxs[wv * 32 + tt * 16 + lane] = bi;
            if (s2 - b < MARGIN) {
                int pos = atomicAdd((int*)ws + OFF_RCNT, 1);
                if (pos < RCAP) ((int*)ws)[OFF_RLIST + pos] = token;
            }
        }
    }
    __syncthreads();

    // fused quantized + loss epilogue (refine later corrects flagged rows)
    float se = 0.f;
    int tokb0 = blockIdx.x * 128;
#pragma unroll
    for (int i = 0; i < 8; ++i) {
        int gi = i * 256 + tid;
        int tok = gi >> 4, qd = gi & 15;
        int ci = idxs[tok];
        float4 xvv = *(const float4*)(x + (size_t)(tokb0 + tok) * 64 + qd * 4);
        float4 qv = *(const float4*)(cbf + (size_t)ci * 64 + qd * 4);
        float d0 = qv.x - xvv.x, d1 = qv.y - xvv.y;
        float d2 = qv.z - xvv.z, d3 = qv.w - xvv.w;
        float4 o;
        o.x = xvv.x + d0; o.y = xvv.y + d1; o.z = xvv.z + d2; o.w = xvv.w + d3;
        *(float4*)(out + (size_t)(tokb0 + tok) * 64 + qd * 4) = o;
        se += d0 * d0 + d1 * d1 + d2 * d2 + d3 * d3;
    }
    for (int off = 32; off; off >>= 1) se += __shfl_down(se, off, 64);
    if (lane == 0) red[wv] = se;
    __syncthreads();
    if (tid == 0) ws[OFF_BLK + blockIdx.x] = (red[0] + red[1]) + (red[2] + red[3]);
}

// exact fp32 re-scan for flagged tokens; fixes quantized rows + loss delta.
__global__ __launch_bounds__(256) void vq_refine(const float* __restrict__ x,
                                                 const float* __restrict__ cb,
                                                 float* __restrict__ out,
                                                 float* __restrict__ ws) {
    __shared__ float ctile[128][64];               // 32KB
    __shared__ float xs[8][64];
    __shared__ float As[8];
    __shared__ int   tokid[8], oidx[8], nidx[8];
    __shared__ unsigned long long rkeys[8][128];   // 8KB
    __shared__ float dred[4];

    int cnt = min(((int*)ws)[OFF_RCNT], RCAP);
    if (cnt <= 0) return;
    int ngroups = (cnt + 7) >> 3;
    int tid = threadIdx.x;
    int code = tid & 127, th = tid >> 7;

    for (int grp = blockIdx.x; grp < ngroups; grp += gridDim.x) {
        if (tid < 8) {
            int i = grp * 8 + tid;
            int t = ((int*)ws)[OFF_RLIST + min(i, cnt - 1)];
            tokid[tid] = t;
            oidx[tid] = (int)out[IDXOFF + t];
        }
        __syncthreads();
#pragma unroll
        for (int it = 0; it < 2; ++it) {
            int idx = it * 256 + tid;
            xs[idx >> 6][idx & 63] = x[(size_t)tokid[idx >> 6] * 64 + (idx & 63)];
        }
        __syncthreads();
        if (tid < 8) {   // exact R2 A-chain
            float a0 = 0.f, a1 = 0.f, a2 = 0.f, a3 = 0.f;
#pragma unroll
            for (int kc = 0; kc < 16; ++kc) {
                float4 xk = *(const float4*)(xs[tid] + kc * 4);
                a0 = fmaf(xk.x, xk.x, a0); a1 = fmaf(xk.y, xk.y, a1);
                a2 = fmaf(xk.z, xk.z, a2); a3 = fmaf(xk.w, xk.w, a3);
            }
            As[tid] = (a0 + a1) + (a2 + a3);
        }

        unsigned long long bk[4] = {~0ull, ~0ull, ~0ull, ~0ull};
        int tb = th * 4;

        for (int pass = 0; pass < 8; ++pass) {
            int cbase = pass * 128;
            __syncthreads();
#pragma unroll
            for (int it = 0; it < 8; ++it) {
                int gi = it * 256 + tid;
                int cc = gi >> 4, qq = gi & 15;
                float4 v = *(const float4*)(cb + (size_t)(cbase + cc) * 64 + qq * 4);
                *(float4*)&ctile[cc][(qq ^ (cc & 15)) * 4] = v;
            }
            __syncthreads();

            float p0 = 0.f, p1 = 0.f, p2 = 0.f, p3 = 0.f;
#pragma unroll
            for (int qq = 0; qq < 16; ++qq) {
                float4 cv = *(const float4*)&ctile[code][(qq ^ (code & 15)) * 4];
                float4 x0 = *(const float4*)(xs[tb + 0] + qq * 4);
                float4 x1 = *(const float4*)(xs[tb + 1] + qq * 4);
                float4 x2 = *(const float4*)(xs[tb + 2] + qq * 4);
                float4 x3 = *(const float4*)(xs[tb + 3] + qq * 4);
                p0 = fmaf(x0.x, cv.x, p0); p0 = fmaf(x0.y, cv.y, p0);
                p0 = fmaf(x0.z, cv.z, p0); p0 = fmaf(x0.w, cv.w, p0);
                p1 = fmaf(x1.x, cv.x, p1); p1 = fmaf(x1.y, cv.y, p1);
                p1 = fmaf(x1.z, cv.z, p1); p1 = fmaf(x1.w, cv.w, p1);
                p2 = fmaf(x2.x, cv.x, p2); p2 = fmaf(x2.y, cv.y, p2);
                p2 = fmaf(x2.z, cv.z, p2); p2 = fmaf(x2.w, cv.w, p2);
                p3 = fmaf(x3.x, cv.x, p3); p3 = fmaf(x3.y, cv.y, p3);
                p3 = fmaf(x3.z, cv.z, p3); p3 = fmaf(x3.w, cv.w, p3);
            }
            float bn = ws[OFF_BC + cbase + code];
            int gcode = cbase + code;
            float pv[4] = {p0, p1, p2, p3};
#pragma unroll
            for (int j = 0; j < 4; ++j) {
                float s = As[tb + j] + bn;
                float d = fmaf(-2.0f, pv[j], s);   // == fl(s - 2p)
                unsigned long long key =
                    (((unsigned long long)__float_as_uint(d)) << 32) | (unsigned)gcode;
                bk[j] = min(bk[j], key);
            }
        }
        __syncthreads();
#pragma unroll
        for (int j = 0; j < 4; ++j) rkeys[tb + j][code] = bk[j];
        __syncthreads();

        int wv2 = tid >> 6, lane = tid & 63;
#pragma unroll
        for (int u = 0; u < 2; ++u) {
            int tt = wv2 * 2 + u;
            unsigned long long k = min(rkeys[tt][lane], rkeys[tt][lane + 64]);
#pragma unroll
            for (int off = 32; off; off >>= 1)
                k = min(k, (unsigned long long)__shfl_xor((long long)k, off, 64));
            if (lane == 0) {
                int ni = (int)(unsigned)(k & 0xffffffffull);
                nidx[tt] = ni;
                if (grp * 8 + tt < cnt) out[IDXOFF + tokid[tt]] = (float)ni;
            }
        }
        __syncthreads();

        float delta = 0.f;
        {
            int tok = tid >> 5, e2 = (tid & 31) * 2;
            if (grp * 8 + tok < cnt) {
                int nw = nidx[tok], od = oidx[tok];
                if (nw != od) {
                    float x0 = xs[tok][e2], x1 = xs[tok][e2 + 1];
                    float qn0 = cb[(size_t)nw * 64 + e2], qn1 = cb[(size_t)nw * 64 + e2 + 1];
                    float qo0 = cb[(size_t)od * 64 + e2], qo1 = cb[(size_t)od * 64 + e2 + 1];
                    float dn0 = qn0 - x0, dn1 = qn1 - x1;
                    float do0 = qo0 - x0, do1 = qo1 - x1;
                    out[(size_t)tokid[tok] * 64 + e2]     = x0 + dn0;
                    out[(size_t)tokid[tok] * 64 + e2 + 1] = x1 + dn1;
                    delta = (dn0 * dn0 + dn1 * dn1) - (do0 * do0 + do1 * do1);
                }
            }
        }
        for (int off = 32; off; off >>= 1) delta += __shfl_down(delta, off, 64);
        if ((tid & 63) == 0) dred[tid >> 6] = delta;
        __syncthreads();
        if (tid == 0) {
            float dsum = (dred[0] + dred[1]) + (dred[2] + dred[3]);
            if (dsum != 0.f) atomicAdd(ws + OFF_CORR, dsum);
        }
        __syncthreads();
    }
}

__global__ __launch_bounds__(256) void vq_loss2(float* __restrict__ out,
                                                const float* __restrict__ ws) {
    const float* blk = ws + OFF_BLK;
    __shared__ double sd[256];
    double s = 0.0;
    for (int i = threadIdx.x; i < 2048; i += 256) s += (double)blk[i];
    sd[threadIdx.x] = s;
    __syncthreads();
    for (int off = 128; off; off >>= 1) {
        if (threadIdx.x < off) sd[threadIdx.x] += sd[threadIdx.x + off];
        __syncthreads();
    }
    if (threadIdx.x == 0) {
        double tot = sd[0] + (double)ws[OFF_CORR];
        out[LOSSOFF] = (float)(1.25 * tot / ((double)NTOK * (double)DIM));
    }
}

extern "C" void kernel_launch(void* const* d_in, const int* in_sizes, int n_in,
                              void* d_out, int out_size, void* d_ws, size_t ws_size,
                              hipStream_t stream) {
    (void)in_sizes; (void)n_in; (void)out_size; (void)ws_size;
    const float* x = (const float*)d_in[0];
    const float* cb = (const float*)d_in[1];
    float* out = (float*)d_out;
    float* ws = (float*)d_ws;

    hipLaunchKernelGGL(vq_prep_cb, dim3(4), dim3(256), 0, stream, cb, ws);
    hipLaunchKernelGGL(vq_mfma, dim3(2048), dim3(256), 0, stream, x, cb, out, ws);
    hipLaunchKernelGGL(vq_refine, dim3(1024), dim3(256), 0, stream, x, cb, out, ws);
    hipLaunchKernelGGL(vq_loss2, dim3(1), dim3(256), 0, stream, out, ws);
}

// Round 26
// 149.713 us; speedup vs baseline: 2.3964x; 2.3964x over previous
//
#include <hip/hip_runtime.h>
#include <math.h>

#define NTOK   262144
#define DIM    64
#define NCODE  1024
#define LOSSOFF (NTOK*DIM)          // 16777216
#define IDXOFF  (NTOK*DIM + 1)

// Margin covers: ref's fp32 quantization reorder (2*ulp(D~64..128) ~ 3.05e-5
// worst tail) + MFMA-split dd error (<= ~3e-7). 4e-5 holds with headroom.
// (R25 lesson: wide margins lose -- refine cost ~linear in flag rate.)
#define MARGIN 4e-5f
#define RCAP   65536

// ws float-offsets
#define OFF_BC     0               // 1024 f
#define OFF_CBHI   1024            // ushort[65536] = 32768 f
#define OFF_CBMID  33792           // 32768 f
#define OFF_RCNT   66560           // 1 int
#define OFF_CORR   66561           // 1 float
#define OFF_RLIST  66562           // 65536 int
#define OFF_BLK    132098          // 2048 f
#define WS_FLOATS  134146

typedef __attribute__((ext_vector_type(8))) short short8;
typedef __attribute__((ext_vector_type(4))) float f32x4;

__device__ __forceinline__ ushort bf16rn(float f) {
    unsigned u = __float_as_uint(f);
    return (ushort)((u + 0x7fffu + ((u >> 16) & 1u)) >> 16);
}
__device__ __forceinline__ float bf16tof(ushort h) {
    return __uint_as_float(((unsigned)h) << 16);
}

__global__ __launch_bounds__(256) void vq_prep_cb(const float* __restrict__ cb,
                                                  float* __restrict__ ws) {
    int c = blockIdx.x * 256 + threadIdx.x;
    if (c == 0) { ((int*)ws)[OFF_RCNT] = 0; ws[OFF_CORR] = 0.f; }
    if (c >= NCODE) return;
    ushort* cbh = (ushort*)(ws + OFF_CBHI);
    ushort* cbm = (ushort*)(ws + OFF_CBMID);
    const float4* p = (const float4*)(cb + (size_t)c * DIM);
    float a0 = 0.f, a1 = 0.f, a2 = 0.f, a3 = 0.f;
#pragma unroll
    for (int i = 0; i < 16; i++) {
        float4 v = p[i];
        a0 = fmaf(v.x, v.x, a0); a1 = fmaf(v.y, v.y, a1);
        a2 = fmaf(v.z, v.z, a2); a3 = fmaf(v.w, v.w, a3);
        ushort4 h, m;
        h.x = bf16rn(v.x); m.x = bf16rn(v.x - bf16tof(h.x));
        h.y = bf16rn(v.y); m.y = bf16rn(v.y - bf16tof(h.y));
        h.z = bf16rn(v.z); m.z = bf16rn(v.z - bf16tof(h.z));
        h.w = bf16rn(v.w); m.w = bf16rn(v.w - bf16tof(h.w));
        ((ushort4*)(cbh + (size_t)c * 64))[i] = h;
        ((ushort4*)(cbm + (size_t)c * 64))[i] = m;
    }
    ws[OFF_BC + c] = (a0 + a1) + (a2 + a3);   // exact R2 prep chain
}

// R18 champion (126us: single-barrier ping-pong, waves_per_eu(3), single
// 6-MFMA chain) + ONE isolated fix: Bc staged to LDS in the prologue.
// Mechanism (R22 analysis): vmcnt retires IN ORDER; the inner-loop bq
// global load was younger than the round's prefetch loads, so waiting on
// bq drained the prefetch slack every round. With Bc on the lgkm path the
// K-loop has zero VMEM consumers -- prefetch keeps its full 2-round slack.
// Distances bit-identical to R18.
__global__ __launch_bounds__(256)
__attribute__((amdgpu_waves_per_eu(3)))
void vq_mfma(const float* __restrict__ x,
             const float* __restrict__ cbf,
             float* __restrict__ out,
             float* __restrict__ ws) {
    __shared__ uint4 smem[8][256];   // 32KB: sets [0..3] / [4..7]
    __shared__ float bcs[1024];      // 4KB: Bc (lgkm broadcast reads)
    __shared__ int idxs[128];
    __shared__ float red[4];
    const float* Bc = ws + OFF_BC;
    const ushort* cbh = (const ushort*)(ws + OFF_CBHI);
    const ushort* cbm = (const ushort*)(ws + OFF_CBMID);

    int tid = threadIdx.x, lane = tid & 63, wv = tid >> 6;
    int col = lane & 15, q = lane >> 4, q4 = q * 4;
    int tokb = blockIdx.x * 128 + wv * 32;

    short8 Xhi[2][2], Xmid[2][2];
#pragma unroll
    for (int tt = 0; tt < 2; ++tt) {
        int token = tokb + tt * 16 + col;
        const float* xr = x + (size_t)token * 64;
#pragma unroll
        for (int s = 0; s < 2; ++s) {
            float4 v0 = *(const float4*)(xr + s * 32 + q * 8);
            float4 v1 = *(const float4*)(xr + s * 32 + q * 8 + 4);
            float vv[8] = {v0.x, v0.y, v0.z, v0.w, v1.x, v1.y, v1.z, v1.w};
            short8 hv, mv;
#pragma unroll
            for (int j = 0; j < 8; ++j) {
                ushort h = bf16rn(vv[j]);
                float r = vv[j] - bf16tof(h);   // exact (Sterbenz)
                hv[j] = (short)h; mv[j] = (short)bf16rn(r);
            }
            Xhi[tt][s] = hv; Xmid[tt][s] = mv;
        }
    }

    // Bc -> LDS once (covered by the prologue barrier)
    *(float4*)&bcs[tid * 4] = *(const float4*)(Bc + tid * 4);

    float best[2][4], sec[2][4];
    int bbase[2][4];
#pragma unroll
    for (int tt = 0; tt < 2; ++tt)
#pragma unroll
        for (int rr = 0; rr < 4; ++rr) {
            best[tt][rr] = 3.4e38f; sec[tt][rr] = 3.4e38f; bbase[tt][rr] = 0;
        }

    int chunk = tid >> 7, e = tid & 127, scode = e >> 3, g = e & 7;
    const ushort* sb0 = (chunk ? cbm : cbh) + (size_t)scode * 64 + g * 8;
    int woff = chunk * 128 + scode * 8 + (g ^ (scode & 7));
    int ro_h0 = col * 8 + ((0 + q) ^ (col & 7));
    int ro_h1 = col * 8 + ((4 + q) ^ (col & 7));
    int ro_m0 = 128 + col * 8 + ((0 + q) ^ (col & 7));
    int ro_m1 = 128 + col * 8 + ((4 + q) ^ (col & 7));

    // prefill: tiles 0..3 into set A; issue loads for tiles 4..7
    uint4 r0 = *(const uint4*)(sb0);
    uint4 r1 = *(const uint4*)(sb0 + 1024);
    uint4 r2 = *(const uint4*)(sb0 + 2048);
    uint4 r3 = *(const uint4*)(sb0 + 3072);
    smem[0][woff] = r0; smem[1][woff] = r1;
    smem[2][woff] = r2; smem[3][woff] = r3;
    r0 = *(const uint4*)(sb0 + 4096);
    r1 = *(const uint4*)(sb0 + 5120);
    r2 = *(const uint4*)(sb0 + 6144);
    r3 = *(const uint4*)(sb0 + 7168);
    __syncthreads();

    for (int rd = 0; rd < 16; ++rd) {
        int base = (rd & 1) << 2;    // set being read
        int nb = 4 - base;           // set being written (next round's tiles)
        if (rd < 15) {
            smem[nb + 0][woff] = r0; smem[nb + 1][woff] = r1;
            smem[nb + 2][woff] = r2; smem[nb + 3][woff] = r3;
            if (rd < 14) {           // loads for round rd+2 (full-round slack,
                                     // now undisturbed: no other VMEM in loop)
                const ushort* ld = sb0 + (size_t)(rd + 2) * 4096;
                r0 = *(const uint4*)(ld);
                r1 = *(const uint4*)(ld + 1024);
                r2 = *(const uint4*)(ld + 2048);
                r3 = *(const uint4*)(ld + 3072);
            }
        }
#pragma unroll
        for (int sub = 0; sub < 4; ++sub) {
            int c0 = (rd * 4 + sub) * 16;
            float4 bq = *(const float4*)&bcs[c0 + q4];   // LDS broadcast
            short8 Ah0 = *(const short8*)&smem[base + sub][ro_h0];
            short8 Ah1 = *(const short8*)&smem[base + sub][ro_h1];
            short8 Am0 = *(const short8*)&smem[base + sub][ro_m0];
            short8 Am1 = *(const short8*)&smem[base + sub][ro_m1];
            int bv = c0 + q4;
            float bqv[4] = {bq.x, bq.y, bq.z, bq.w};
#pragma unroll
            for (int tt = 0; tt < 2; ++tt) {
                f32x4 acc = {0.f, 0.f, 0.f, 0.f};
                acc = __builtin_amdgcn_mfma_f32_16x16x32_bf16(Ah0, Xhi[tt][0], acc, 0, 0, 0);
                acc = __builtin_amdgcn_mfma_f32_16x16x32_bf16(Ah1, Xhi[tt][1], acc, 0, 0, 0);
                acc = __builtin_amdgcn_mfma_f32_16x16x32_bf16(Ah0, Xmid[tt][0], acc, 0, 0, 0);
                acc = __builtin_amdgcn_mfma_f32_16x16x32_bf16(Ah1, Xmid[tt][1], acc, 0, 0, 0);
                acc = __builtin_amdgcn_mfma_f32_16x16x32_bf16(Am0, Xhi[tt][0], acc, 0, 0, 0);
                acc = __builtin_amdgcn_mfma_f32_16x16x32_bf16(Am1, Xhi[tt][1], acc, 0, 0, 0);
#pragma unroll
                for (int rr = 0; rr < 4; ++rr) {
                    float d = fmaf(-2.f, acc[rr], bqv[rr]);
                    bool lt = d < best[tt][rr];
                    sec[tt][rr] = __builtin_amdgcn_fmed3f(d, best[tt][rr], sec[tt][rr]);
                    best[tt][rr] = fminf(best[tt][rr], d);
                    bbase[tt][rr] = lt ? bv : bbase[tt][rr];
                }
            }
        }
        __syncthreads();   // single barrier per round
    }

#pragma unroll
    for (int tt = 0; tt < 2; ++tt) {
        float b = best[tt][0], s2 = sec[tt][0];
        int bi = bbase[tt][0];
#pragma unroll
        for (int rr = 1; rr < 4; ++rr) {
            float ob = best[tt][rr];
            int oi = bbase[tt][rr] + rr;
            s2 = fminf(fminf(s2, sec[tt][rr]), fmaxf(b, ob));
            bool lt2 = (ob < b) || (ob == b && oi < bi);
            b = lt2 ? ob : b; bi = lt2 ? oi : bi;
        }
#pragma unroll
        for (int off = 16; off <= 32; off <<= 1) {
            float ob = __shfl_xor(b, off, 64);
            float os = __shfl_xor(s2, off, 64);
            int   oi = __shfl_xor(bi, off, 64);
            s2 = fminf(fminf(s2, os), fmaxf(b, ob));
            bool lt = (ob < b) || (ob == b && oi < bi);
            b = lt ? ob : b; bi = lt ? oi : bi;
        }
        if (lane < 16) {
            int token = tokb + tt * 16 + lane;
            out[IDXOFF + token] = (float)bi;
            idxs[wv * 32 + tt * 16 + lane] = bi;
            if (s2 - b < MARGIN) {
                int pos = atomicAdd((int*)ws + OFF_RCNT, 1);
                if (pos < RCAP) ((int*)ws)[OFF_RLIST + pos] = token;
            }
        }
    }
    __syncthreads();

    // fused quantized + loss epilogue (refine later corrects flagged rows)
    float se = 0.f;
    int tokb0 = blockIdx.x * 128;
#pragma unroll
    for (int i = 0; i < 8; ++i) {
        int gi = i * 256 + tid;
        int tok = gi >> 4, qd = gi & 15;
        int ci = idxs[tok];
        float4 xvv = *(const float4*)(x + (size_t)(tokb0 + tok) * 64 + qd * 4);
        float4 qv = *(const float4*)(cbf + (size_t)ci * 64 + qd * 4);
        float d0 = qv.x - xvv.x, d1 = qv.y - xvv.y;
        float d2 = qv.z - xvv.z, d3 = qv.w - xvv.w;
        float4 o;
        o.x = xvv.x + d0; o.y = xvv.y + d1; o.z = xvv.z + d2; o.w = xvv.w + d3;
        *(float4*)(out + (size_t)(tokb0 + tok) * 64 + qd * 4) = o;
        se += d0 * d0 + d1 * d1 + d2 * d2 + d3 * d3;
    }
    for (int off = 32; off; off >>= 1) se += __shfl_down(se, off, 64);
    if (lane == 0) red[wv] = se;
    __syncthreads();
    if (tid == 0) ws[OFF_BLK + blockIdx.x] = (red[0] + red[1]) + (red[2] + red[3]);
}

// exact fp32 re-scan for flagged tokens; fixes quantized rows + loss delta.
__global__ __launch_bounds__(256) void vq_refine(const float* __restrict__ x,
                                                 const float* __restrict__ cb,
                                                 float* __restrict__ out,
                                                 float* __restrict__ ws) {
    __shared__ float ctile[128][64];               // 32KB
    __shared__ float xs[8][64];
    __shared__ float As[8];
    __shared__ int   tokid[8], oidx[8], nidx[8];
    __shared__ unsigned long long rkeys[8][128];   // 8KB
    __shared__ float dred[4];

    int cnt = min(((int*)ws)[OFF_RCNT], RCAP);
    if (cnt <= 0) return;
    int ngroups = (cnt + 7) >> 3;
    int tid = threadIdx.x;
    int code = tid & 127, th = tid >> 7;

    for (int grp = blockIdx.x; grp < ngroups; grp += gridDim.x) {
        if (tid < 8) {
            int i = grp * 8 + tid;
            int t = ((int*)ws)[OFF_RLIST + min(i, cnt - 1)];
            tokid[tid] = t;
            oidx[tid] = (int)out[IDXOFF + t];
        }
        __syncthreads();
#pragma unroll
        for (int it = 0; it < 2; ++it) {
            int idx = it * 256 + tid;
            xs[idx >> 6][idx & 63] = x[(size_t)tokid[idx >> 6] * 64 + (idx & 63)];
        }
        __syncthreads();
        if (tid < 8) {   // exact R2 A-chain
            float a0 = 0.f, a1 = 0.f, a2 = 0.f, a3 = 0.f;
#pragma unroll
            for (int kc = 0; kc < 16; ++kc) {
                float4 xk = *(const float4*)(xs[tid] + kc * 4);
                a0 = fmaf(xk.x, xk.x, a0); a1 = fmaf(xk.y, xk.y, a1);
                a2 = fmaf(xk.z, xk.z, a2); a3 = fmaf(xk.w, xk.w, a3);
            }
            As[tid] = (a0 + a1) + (a2 + a3);
        }

        unsigned long long bk[4] = {~0ull, ~0ull, ~0ull, ~0ull};
        int tb = th * 4;

        for (int pass = 0; pass < 8; ++pass) {
            int cbase = pass * 128;
            __syncthreads();
#pragma unroll
            for (int it = 0; it < 8; ++it) {
                int gi = it * 256 + tid;
                int cc = gi >> 4, qq = gi & 15;
                float4 v = *(const float4*)(cb + (size_t)(cbase + cc) * 64 + qq * 4);
                *(float4*)&ctile[cc][(qq ^ (cc & 15)) * 4] = v;
            }
            __syncthreads();

            float p0 = 0.f, p1 = 0.f, p2 = 0.f, p3 = 0.f;
#pragma unroll
            for (int qq = 0; qq < 16; ++qq) {
                float4 cv = *(const float4*)&ctile[code][(qq ^ (code & 15)) * 4];
                float4 x0 = *(const float4*)(xs[tb + 0] + qq * 4);
                float4 x1 = *(const float4*)(xs[tb + 1] + qq * 4);
                float4 x2 = *(const float4*)(xs[tb + 2] + qq * 4);
                float4 x3 = *(const float4*)(xs[tb + 3] + qq * 4);
                p0 = fmaf(x0.x, cv.x, p0); p0 = fmaf(x0.y, cv.y, p0);
                p0 = fmaf(x0.z, cv.z, p0); p0 = fmaf(x0.w, cv.w, p0);
                p1 = fmaf(x1.x, cv.x, p1); p1 = fmaf(x1.y, cv.y, p1);
                p1 = fmaf(x1.z, cv.z, p1); p1 = fmaf(x1.w, cv.w, p1);
                p2 = fmaf(x2.x, cv.x, p2); p2 = fmaf(x2.y, cv.y, p2);
                p2 = fmaf(x2.z, cv.z, p2); p2 = fmaf(x2.w, cv.w, p2);
                p3 = fmaf(x3.x, cv.x, p3); p3 = fmaf(x3.y, cv.y, p3);
                p3 = fmaf(x3.z, cv.z, p3); p3 = fmaf(x3.w, cv.w, p3);
            }
            float bn = ws[OFF_BC + cbase + code];
            int gcode = cbase + code;
            float pv[4] = {p0, p1, p2, p3};
#pragma unroll
            for (int j = 0; j < 4; ++j) {
                float s = As[tb + j] + bn;
                float d = fmaf(-2.0f, pv[j], s);   // == fl(s - 2p)
                unsigned long long key =
                    (((unsigned long long)__float_as_uint(d)) << 32) | (unsigned)gcode;
                bk[j] = min(bk[j], key);
            }
        }
        __syncthreads();
#pragma unroll
        for (int j = 0; j < 4; ++j) rkeys[tb + j][code] = bk[j];
        __syncthreads();

        int wv2 = tid >> 6, lane = tid & 63;
#pragma unroll
        for (int u = 0; u < 2; ++u) {
            int tt = wv2 * 2 + u;
            unsigned long long k = min(rkeys[tt][lane], rkeys[tt][lane + 64]);
#pragma unroll
            for (int off = 32; off; off >>= 1)
                k = min(k, (unsigned long long)__shfl_xor((long long)k, off, 64));
            if (lane == 0) {
                int ni = (int)(unsigned)(k & 0xffffffffull);
                nidx[tt] = ni;
                if (grp * 8 + tt < cnt) out[IDXOFF + tokid[tt]] = (float)ni;
            }
        }
        __syncthreads();

        float delta = 0.f;
        {
            int tok = tid >> 5, e2 = (tid & 31) * 2;
            if (grp * 8 + tok < cnt) {
                int nw = nidx[tok], od = oidx[tok];
                if (nw != od) {
                    float x0 = xs[tok][e2], x1 = xs[tok][e2 + 1];
                    float qn0 = cb[(size_t)nw * 64 + e2], qn1 = cb[(size_t)nw * 64 + e2 + 1];
                    float qo0 = cb[(size_t)od * 64 + e2], qo1 = cb[(size_t)od * 64 + e2 + 1];
                    float dn0 = qn0 - x0, dn1 = qn1 - x1;
                    float do0 = qo0 - x0, do1 = qo1 - x1;
                    out[(size_t)tokid[tok] * 64 + e2]     = x0 + dn0;
                    out[(size_t)tokid[tok] * 64 + e2 + 1] = x1 + dn1;
                    delta = (dn0 * dn0 + dn1 * dn1) - (do0 * do0 + do1 * do1);
                }
            }
        }
        for (int off = 32; off; off >>= 1) delta += __shfl_down(delta, off, 64);
        if ((tid & 63) == 0) dred[tid >> 6] = delta;
        __syncthreads();
        if (tid == 0) {
            float dsum = (dred[0] + dred[1]) + (dred[2] + dred[3]);
            if (dsum != 0.f) atomicAdd(ws + OFF_CORR, dsum);
        }
        __syncthreads();
    }
}

__global__ __launch_bounds__(256) void vq_loss2(float* __restrict__ out,
                                                const float* __restrict__ ws) {
    const float* blk = ws + OFF_BLK;
    __shared__ double sd[256];
    double s = 0.0;
    for (int i = threadIdx.x; i < 2048; i += 256) s += (double)blk[i];
    sd[threadIdx.x] = s;
    __syncthreads();
    for (int off = 128; off; off >>= 1) {
        if (threadIdx.x < off) sd[threadIdx.x] += sd[threadIdx.x + off];
        __syncthreads();
    }
    if (threadIdx.x == 0) {
        double tot = sd[0] + (double)ws[OFF_CORR];
        out[LOSSOFF] = (float)(1.25 * tot / ((double)NTOK * (double)DIM));
    }
}

extern "C" void kernel_launch(void* const* d_in, const int* in_sizes, int n_in,
                              void* d_out, int out_size, void* d_ws, size_t ws_size,
                              hipStream_t stream) {
    (void)in_sizes; (void)n_in; (void)out_size; (void)ws_size;
    const float* x = (const float*)d_in[0];
    const float* cb = (const float*)d_in[1];
    float* out = (float*)d_out;
    float* ws = (float*)d_ws;

    hipLaunchKernelGGL(vq_prep_cb, dim3(4), dim3(256), 0, stream, cb, ws);
    hipLaunchKernelGGL(vq_mfma, dim3(2048), dim3(256), 0, stream, x, cb, out, ws);
    hipLaunchKernelGGL(vq_refine, dim3(1024), dim3(256), 0, stream, x, cb, out, ws);
    hipLaunchKernelGGL(vq_loss2, dim3(1), dim3(256), 0, stream, out, ws);
}